// Round 1
// baseline (2085.298 us; speedup 1.0000x reference)
//
#include <hip/hip_runtime.h>

#define D_FEAT 64

// One wave = one edge; lane f handles feature f.
// out[dst[e]*64 + f] += h[src[e]*64 + f] * w[e]
__global__ void IU_GCN_scatter_hop(const float* __restrict__ h,
                                   const float* __restrict__ w,
                                   const int* __restrict__ src,
                                   const int* __restrict__ dst,
                                   float* __restrict__ out,
                                   long long total) {
    long long idx = (long long)blockIdx.x * blockDim.x + threadIdx.x;
    if (idx >= total) return;
    int e = (int)(idx >> 6);       // edge index (wave-uniform)
    int f = (int)(idx & 63);       // feature index = lane
    int s = src[e];
    int d = dst[e];
    float val = h[(long long)s * D_FEAT + f] * w[e];
    atomicAdd(&out[(long long)d * D_FEAT + f], val);
}

extern "C" void kernel_launch(void* const* d_in, const int* in_sizes, int n_in,
                              void* d_out, int out_size, void* d_ws, size_t ws_size,
                              hipStream_t stream) {
    const float* x   = (const float*)d_in[0];
    const float* ew  = (const float*)d_in[1];
    const int*   src = (const int*)d_in[2];
    const int*   dst = (const int*)d_in[3];
    float* out = (float*)d_out;

    const int n_nodes = in_sizes[0] / D_FEAT;   // 100000
    const int n_edges = in_sizes[1];            // 3200000

    const size_t nf_bytes = (size_t)n_nodes * D_FEAT * sizeof(float);
    float* bufA = (float*)d_ws;                 // one ping-pong buffer (25.6 MB)

    const long long total = (long long)n_edges * D_FEAT;
    const int block = 256;
    const int grid = (int)((total + block - 1) / block);

    // hop 1: x -> out
    hipMemsetAsync(out, 0, nf_bytes, stream);
    IU_GCN_scatter_hop<<<grid, block, 0, stream>>>(x, ew, src, dst, out, total);

    // hop 2: out -> bufA
    hipMemsetAsync(bufA, 0, nf_bytes, stream);
    IU_GCN_scatter_hop<<<grid, block, 0, stream>>>(out, ew, src, dst, bufA, total);

    // hop 3: bufA -> out
    hipMemsetAsync(out, 0, nf_bytes, stream);
    IU_GCN_scatter_hop<<<grid, block, 0, stream>>>(bufA, ew, src, dst, out, total);
}

// Round 2
// 1134.794 us; speedup vs baseline: 1.8376x; 1.8376x over previous
//
#include <hip/hip_runtime.h>

#define D_FEAT 64

// ---------- CSR build ----------
__global__ void hist_kernel(const int* __restrict__ dst, int* __restrict__ counts, int n_edges) {
    int e = blockIdx.x * blockDim.x + threadIdx.x;
    if (e < n_edges) atomicAdd(&counts[dst[e]], 1);
}

// Single-workgroup blocked exclusive scan over n counts -> row_ptr[0..n], offsets[0..n-1]
__global__ void scan_kernel(const int* __restrict__ counts, int* __restrict__ row_ptr,
                            int* __restrict__ offsets, int n) {
    __shared__ int lds[1024];
    int t = threadIdx.x;
    int chunk = (n + 1023) >> 10;
    int beg = min(t * chunk, n);
    int end = min(beg + chunk, n);
    int s = 0;
    for (int i = beg; i < end; ++i) s += counts[i];
    lds[t] = s;
    __syncthreads();
    // Hillis-Steele inclusive scan over 1024 partials
    for (int off = 1; off < 1024; off <<= 1) {
        int v = (t >= off) ? lds[t - off] : 0;
        __syncthreads();
        lds[t] += v;
        __syncthreads();
    }
    int run = (t == 0) ? 0 : lds[t - 1];
    for (int i = beg; i < end; ++i) {
        row_ptr[i] = run;
        offsets[i] = run;
        run += counts[i];
    }
    if (t == 1023) row_ptr[n] = run;   // total = n_edges
}

__global__ void scatter_build(const int* __restrict__ src, const float* __restrict__ w,
                              const int* __restrict__ dst, int* __restrict__ offsets,
                              int2* __restrict__ edges, int n_edges) {
    int e = blockIdx.x * blockDim.x + threadIdx.x;
    if (e >= n_edges) return;
    int d = dst[e];
    int pos = atomicAdd(&offsets[d], 1);
    edges[pos] = make_int2(src[e], __float_as_int(w[e]));
}

// ---------- gather hop: one wave per node, lane = feature ----------
__global__ void gather_hop(const float* __restrict__ h, const int2* __restrict__ edges,
                           const int* __restrict__ row_ptr, float* __restrict__ out,
                           int n_nodes) {
    int node = blockIdx.x * (blockDim.x >> 6) + (threadIdx.x >> 6);
    if (node >= n_nodes) return;
    int f = threadIdx.x & 63;
    int beg = row_ptr[node];
    int end = row_ptr[node + 1];
    float acc = 0.0f;
    for (int base = beg; base < end; base += 64) {
        int rem = end - base;
        int2 e = (f < rem) ? edges[base + f] : make_int2(0, 0);   // coalesced 8B/lane
        int cnt = rem < 64 ? rem : 64;
        for (int j = 0; j < cnt; ++j) {
            int   sn = __shfl(e.x, j);
            float wv = __int_as_float(__shfl(e.y, j));
            acc += wv * h[(long long)sn * D_FEAT + f];            // coalesced 256B row read
        }
    }
    out[(long long)node * D_FEAT + f] = acc;                      // coalesced, no atomics
}

extern "C" void kernel_launch(void* const* d_in, const int* in_sizes, int n_in,
                              void* d_out, int out_size, void* d_ws, size_t ws_size,
                              hipStream_t stream) {
    const float* x   = (const float*)d_in[0];
    const float* ew  = (const float*)d_in[1];
    const int*   src = (const int*)d_in[2];
    const int*   dst = (const int*)d_in[3];
    float* out = (float*)d_out;

    const int n_nodes = in_sizes[0] / D_FEAT;   // 100000
    const int n_edges = in_sizes[1];            // 3200000

    const size_t nf_bytes = (size_t)n_nodes * D_FEAT * sizeof(float);

    // workspace layout
    char* ws = (char*)d_ws;
    float* bufA   = (float*)ws;                        ws += nf_bytes;                    // 25.6 MB
    int2*  edges  = (int2*)ws;                         ws += (size_t)n_edges * 8;         // 25.6 MB
    int*   counts = (int*)ws;                          ws += (size_t)n_nodes * 4;
    int*   row_ptr= (int*)ws;                          ws += (size_t)(n_nodes + 1) * 4;
    int*   offsets= (int*)ws;

    // --- CSR build (per launch; deterministic work) ---
    hipMemsetAsync(counts, 0, (size_t)n_nodes * 4, stream);
    {
        int blk = 256, grd = (n_edges + blk - 1) / blk;
        hist_kernel<<<grd, blk, 0, stream>>>(dst, counts, n_edges);
    }
    scan_kernel<<<1, 1024, 0, stream>>>(counts, row_ptr, offsets, n_nodes);
    {
        int blk = 256, grd = (n_edges + blk - 1) / blk;
        scatter_build<<<grd, blk, 0, stream>>>(src, ew, dst, offsets, edges, n_edges);
    }

    // --- 3 gather hops: x -> out -> bufA -> out ---
    const int blk = 256;                                // 4 waves = 4 nodes / block
    const int grd = (n_nodes + 3) / 4;
    gather_hop<<<grd, blk, 0, stream>>>(x,    edges, row_ptr, out,  n_nodes);
    gather_hop<<<grd, blk, 0, stream>>>(out,  edges, row_ptr, bufA, n_nodes);
    gather_hop<<<grd, blk, 0, stream>>>(bufA, edges, row_ptr, out,  n_nodes);
}

// Round 3
// 421.435 us; speedup vs baseline: 4.9481x; 2.6927x over previous
//
#include <hip/hip_runtime.h>

#define D_FEAT 64
#define CHUNK 8192
#define BSHIFT 9
#define BSIZE 512

// ---------- Phase A: bucket histogram (bucket = dst >> 9) ----------
__global__ void bucket_hist(const int* __restrict__ dst, int* __restrict__ bcount, int n_edges) {
    __shared__ int h[256];
    h[threadIdx.x] = 0;
    __syncthreads();
    for (int e = blockIdx.x * blockDim.x + threadIdx.x; e < n_edges; e += gridDim.x * blockDim.x)
        atomicAdd(&h[dst[e] >> BSHIFT], 1);
    __syncthreads();
    int v = h[threadIdx.x];
    if (v) atomicAdd(&bcount[threadIdx.x], v);
}

// ---------- Phase B: scan 256 bucket counts -> bbase, bcursor ----------
__global__ void bucket_scan(const int* __restrict__ bcount, int* __restrict__ bbase,
                            int* __restrict__ bcursor) {
    __shared__ int s[256];
    int t = threadIdx.x;
    int v = bcount[t];
    s[t] = v;
    __syncthreads();
    for (int off = 1; off < 256; off <<= 1) {
        int u = (t >= off) ? s[t - off] : 0;
        __syncthreads();
        s[t] += u;
        __syncthreads();
    }
    int excl = s[t] - v;
    bbase[t] = excl;
    bcursor[t] = excl;
}

// ---------- Phase C: per-chunk counting sort by bucket, contiguous flush ----------
__global__ __launch_bounds__(256) void partition_kernel(
        const int* __restrict__ src, const int* __restrict__ dst,
        const float* __restrict__ w, int* __restrict__ bcursor,
        int2* __restrict__ inter, int n_edges) {
    __shared__ int hist[256];
    __shared__ int lofs[256];
    __shared__ int cur[256];
    __shared__ int gbase[256];
    __shared__ int2 buf[CHUNK];          // 64 KB staging
    int t = threadIdx.x;
    int beg = blockIdx.x * CHUNK;
    int end = min(beg + CHUNK, n_edges);

    hist[t] = 0;
    __syncthreads();
    for (int i = beg + t; i < end; i += 256)
        atomicAdd(&hist[dst[i] >> BSHIFT], 1);
    __syncthreads();
    // exclusive scan of hist
    int v = hist[t];
    lofs[t] = v;
    __syncthreads();
    for (int off = 1; off < 256; off <<= 1) {
        int u = (t >= off) ? lofs[t - off] : 0;
        __syncthreads();
        lofs[t] += u;
        __syncthreads();
    }
    int excl = lofs[t] - v;
    __syncthreads();
    lofs[t] = excl;
    cur[t]  = excl;
    __syncthreads();
    // scatter into LDS, bucket-ordered
    for (int i = beg + t; i < end; i += 256) {
        int d = dst[i];
        int b = d >> BSHIFT;
        int p = atomicAdd(&cur[b], 1);
        buf[p] = make_int2((src[i] << BSHIFT) | (d & (BSIZE - 1)), __float_as_int(w[i]));
    }
    __syncthreads();
    // reserve global ranges
    if (hist[t]) gbase[t] = atomicAdd(&bcursor[t], hist[t]);
    __syncthreads();
    // flush contiguous runs (wave b-strided)
    int wid = t >> 6, lane = t & 63;
    for (int b = wid; b < 256; b += 4) {
        int c = hist[b];
        if (!c) continue;
        int lo = lofs[b], gb = gbase[b];
        for (int k = lane; k < c; k += 64)
            inter[gb + k] = buf[lo + k];
    }
}

// ---------- Phase D: per-bucket counting sort by node; emits row_ptr ----------
__global__ __launch_bounds__(512) void finalize_kernel(
        const int2* __restrict__ inter, const int* __restrict__ bbase,
        const int* __restrict__ bcount, int2* __restrict__ edges,
        int* __restrict__ row_ptr, int n_nodes, int n_edges) {
    __shared__ int hist[BSIZE];
    __shared__ int cur[BSIZE];
    int b = blockIdx.x;
    int t = threadIdx.x;
    int base = bbase[b];
    int cnt  = bcount[b];

    hist[t] = 0;
    __syncthreads();
    for (int i = t; i < cnt; i += BSIZE)
        atomicAdd(&hist[inter[base + i].x & (BSIZE - 1)], 1);
    __syncthreads();
    int v = hist[t];
    cur[t] = v;
    __syncthreads();
    for (int off = 1; off < BSIZE; off <<= 1) {
        int u = (t >= off) ? cur[t - off] : 0;
        __syncthreads();
        cur[t] += u;
        __syncthreads();
    }
    int excl = cur[t] - v;
    int node = (b << BSHIFT) + t;
    if (node < n_nodes) row_ptr[node] = base + excl;
    if (b == 0 && t == 0) row_ptr[n_nodes] = n_edges;
    __syncthreads();
    cur[t] = excl;
    __syncthreads();
    for (int i = t; i < cnt; i += BSIZE) {
        int2 r = inter[base + i];
        int dlo = r.x & (BSIZE - 1);
        int p = atomicAdd(&cur[dlo], 1);
        edges[base + p] = make_int2(r.x >> BSHIFT, r.y);   // (src, w-bits)
    }
}

// ---------- gather hop: one wave per node; scalar edge stream ----------
__global__ __launch_bounds__(256) void gather_hop(
        const float* __restrict__ h, const int2* __restrict__ edges,
        const int* __restrict__ row_ptr, float* __restrict__ out, int n_nodes) {
    int node = __builtin_amdgcn_readfirstlane(blockIdx.x * 4 + (threadIdx.x >> 6));
    if (node >= n_nodes) return;
    int f = threadIdx.x & 63;
    int beg = __builtin_amdgcn_readfirstlane(row_ptr[node]);
    int end = __builtin_amdgcn_readfirstlane(row_ptr[node + 1]);
    float acc = 0.0f;
    int j = beg;
    for (; j + 8 <= end; j += 8) {
        #pragma unroll
        for (int k = 0; k < 8; ++k) {
            int2 ev = edges[j + k];                        // uniform addr -> scalar load
            acc += __int_as_float(ev.y) * h[((size_t)ev.x << 6) + f];
        }
    }
    for (; j < end; ++j) {
        int2 ev = edges[j];
        acc += __int_as_float(ev.y) * h[((size_t)ev.x << 6) + f];
    }
    out[((size_t)node << 6) + f] = acc;
}

extern "C" void kernel_launch(void* const* d_in, const int* in_sizes, int n_in,
                              void* d_out, int out_size, void* d_ws, size_t ws_size,
                              hipStream_t stream) {
    const float* x   = (const float*)d_in[0];
    const float* ew  = (const float*)d_in[1];
    const int*   src = (const int*)d_in[2];
    const int*   dst = (const int*)d_in[3];
    float* out = (float*)d_out;

    const int n_nodes = in_sizes[0] / D_FEAT;   // 100000
    const int n_edges = in_sizes[1];            // 3200000
    const int nbuck   = (n_nodes + BSIZE - 1) >> BSHIFT;   // 196

    const size_t nf_bytes = (size_t)n_nodes * D_FEAT * sizeof(float);
    const size_t ed_bytes = (size_t)n_edges * 8;

    // workspace layout: inter aliases bufA (disjoint lifetimes, both 25.6 MB)
    char* ws = (char*)d_ws;
    float* bufA    = (float*)ws;
    int2*  inter   = (int2*)ws;                ws += (nf_bytes > ed_bytes ? nf_bytes : ed_bytes);
    int2*  edges   = (int2*)ws;                ws += ed_bytes;
    int*   row_ptr = (int*)ws;                 ws += (size_t)(n_nodes + 1) * 4;
    int*   bcount  = (int*)ws;                 ws += 256 * 4;
    int*   bbase   = (int*)ws;                 ws += 256 * 4;
    int*   bcursor = (int*)ws;

    // --- build dst-sorted CSR (bucketed counting sort) ---
    hipMemsetAsync(bcount, 0, 256 * 4, stream);
    bucket_hist<<<512, 256, 0, stream>>>(dst, bcount, n_edges);
    bucket_scan<<<1, 256, 0, stream>>>(bcount, bbase, bcursor);
    partition_kernel<<<(n_edges + CHUNK - 1) / CHUNK, 256, 0, stream>>>(
        src, dst, ew, bcursor, inter, n_edges);
    finalize_kernel<<<nbuck, BSIZE, 0, stream>>>(
        inter, bbase, bcount, edges, row_ptr, n_nodes, n_edges);

    // --- 3 gather hops: x -> out -> bufA -> out (no zeroing needed) ---
    const int grd = (n_nodes + 3) / 4;
    gather_hop<<<grd, 256, 0, stream>>>(x,    edges, row_ptr, out,  n_nodes);
    gather_hop<<<grd, 256, 0, stream>>>(out,  edges, row_ptr, bufA, n_nodes);
    gather_hop<<<grd, 256, 0, stream>>>(bufA, edges, row_ptr, out,  n_nodes);
}

// Round 4
// 326.107 us; speedup vs baseline: 6.3945x; 1.2923x over previous
//
#include <hip/hip_runtime.h>

#define D_FEAT 64
#define CHUNK 8192
#define BSHIFT 9
#define BSIZE 512

typedef unsigned int uint;
typedef unsigned short ushort;

static __device__ __forceinline__ ushort f2bf(float f) {
    uint u = __float_as_uint(f);
    uint r = (u + 0x7fffu + ((u >> 16) & 1u)) >> 16;   // RNE
    return (ushort)r;
}
static __device__ __forceinline__ float bf2f(ushort b) {
    return __uint_as_float(((uint)b) << 16);
}

// ---------- Phase A: bucket histogram (bucket = dst >> 9) ----------
__global__ void bucket_hist(const int* __restrict__ dst, int* __restrict__ bcount, int n_edges) {
    __shared__ int h[256];
    h[threadIdx.x] = 0;
    __syncthreads();
    for (int e = blockIdx.x * blockDim.x + threadIdx.x; e < n_edges; e += gridDim.x * blockDim.x)
        atomicAdd(&h[dst[e] >> BSHIFT], 1);
    __syncthreads();
    int v = h[threadIdx.x];
    if (v) atomicAdd(&bcount[threadIdx.x], v);
}

// ---------- Phase B: scan 256 bucket counts -> bbase, bcursor ----------
__global__ void bucket_scan(const int* __restrict__ bcount, int* __restrict__ bbase,
                            int* __restrict__ bcursor) {
    __shared__ int s[256];
    int t = threadIdx.x;
    int v = bcount[t];
    s[t] = v;
    __syncthreads();
    for (int off = 1; off < 256; off <<= 1) {
        int u = (t >= off) ? s[t - off] : 0;
        __syncthreads();
        s[t] += u;
        __syncthreads();
    }
    int excl = s[t] - v;
    bbase[t] = excl;
    bcursor[t] = excl;
}

// ---------- Phase C: per-chunk counting sort by bucket, contiguous flush ----------
__global__ __launch_bounds__(256) void partition_kernel(
        const int* __restrict__ src, const int* __restrict__ dst,
        const float* __restrict__ w, int* __restrict__ bcursor,
        int2* __restrict__ inter, int n_edges) {
    __shared__ int hist[256];
    __shared__ int lofs[256];
    __shared__ int cur[256];
    __shared__ int gbase[256];
    __shared__ int2 buf[CHUNK];          // 64 KB staging
    int t = threadIdx.x;
    int beg = blockIdx.x * CHUNK;
    int end = min(beg + CHUNK, n_edges);

    hist[t] = 0;
    __syncthreads();
    for (int i = beg + t; i < end; i += 256)
        atomicAdd(&hist[dst[i] >> BSHIFT], 1);
    __syncthreads();
    int v = hist[t];
    lofs[t] = v;
    __syncthreads();
    for (int off = 1; off < 256; off <<= 1) {
        int u = (t >= off) ? lofs[t - off] : 0;
        __syncthreads();
        lofs[t] += u;
        __syncthreads();
    }
    int excl = lofs[t] - v;
    __syncthreads();
    lofs[t] = excl;
    cur[t]  = excl;
    __syncthreads();
    for (int i = beg + t; i < end; i += 256) {
        int d = dst[i];
        int b = d >> BSHIFT;
        int p = atomicAdd(&cur[b], 1);
        buf[p] = make_int2((src[i] << BSHIFT) | (d & (BSIZE - 1)), __float_as_int(w[i]));
    }
    __syncthreads();
    if (hist[t]) gbase[t] = atomicAdd(&bcursor[t], hist[t]);
    __syncthreads();
    int wid = t >> 6, lane = t & 63;
    for (int b = wid; b < 256; b += 4) {
        int c = hist[b];
        if (!c) continue;
        int lo = lofs[b], gb = gbase[b];
        for (int k = lane; k < c; k += 64)
            inter[gb + k] = buf[lo + k];
    }
}

// ---------- Phase D: per-bucket counting sort by node; emits row_ptr ----------
__global__ __launch_bounds__(512) void finalize_kernel(
        const int2* __restrict__ inter, const int* __restrict__ bbase,
        const int* __restrict__ bcount, int2* __restrict__ edges,
        int* __restrict__ row_ptr, int n_nodes, int n_edges) {
    __shared__ int hist[BSIZE];
    __shared__ int cur[BSIZE];
    int b = blockIdx.x;
    int t = threadIdx.x;
    int base = bbase[b];
    int cnt  = bcount[b];

    hist[t] = 0;
    __syncthreads();
    for (int i = t; i < cnt; i += BSIZE)
        atomicAdd(&hist[inter[base + i].x & (BSIZE - 1)], 1);
    __syncthreads();
    int v = hist[t];
    cur[t] = v;
    __syncthreads();
    for (int off = 1; off < BSIZE; off <<= 1) {
        int u = (t >= off) ? cur[t - off] : 0;
        __syncthreads();
        cur[t] += u;
        __syncthreads();
    }
    int excl = cur[t] - v;
    int node = (b << BSHIFT) + t;
    if (node < n_nodes) row_ptr[node] = base + excl;
    if (b == 0 && t == 0) row_ptr[n_nodes] = n_edges;
    __syncthreads();
    cur[t] = excl;
    __syncthreads();
    for (int i = t; i < cnt; i += BSIZE) {
        int2 r = inter[base + i];
        int dlo = r.x & (BSIZE - 1);
        int p = atomicAdd(&cur[dlo], 1);
        edges[base + p] = make_int2(r.x >> BSHIFT, r.y);   // (src, w-bits)
    }
}

// ---------- convert: f32 features -> bf16 ----------
__global__ void cvt_bf16(const float* __restrict__ in, ushort* __restrict__ out, int n) {
    int i = blockIdx.x * blockDim.x + threadIdx.x;
    int stride = gridDim.x * blockDim.x;
    for (; i < n; i += stride) out[i] = f2bf(in[i]);
}

// ---------- gather hop: one wave per node; bf16 row gather, f32 accumulate ----------
template <bool OUT_BF16>
__global__ __launch_bounds__(256) void gather_hop(
        const ushort* __restrict__ h, const int2* __restrict__ edges,
        const int* __restrict__ row_ptr, void* __restrict__ out_v, int n_nodes) {
    int node = __builtin_amdgcn_readfirstlane(blockIdx.x * 4 + (threadIdx.x >> 6));
    if (node >= n_nodes) return;
    int f = threadIdx.x & 63;
    int beg = __builtin_amdgcn_readfirstlane(row_ptr[node]);
    int end = __builtin_amdgcn_readfirstlane(row_ptr[node + 1]);
    float acc = 0.0f;
    int j = beg;
    for (; j + 8 <= end; j += 8) {
        #pragma unroll
        for (int k = 0; k < 8; ++k) {
            int2 ev = edges[j + k];                        // uniform addr -> scalar load
            acc += __int_as_float(ev.y) * bf2f(h[((size_t)ev.x << 6) + f]);
        }
    }
    for (; j < end; ++j) {
        int2 ev = edges[j];
        acc += __int_as_float(ev.y) * bf2f(h[((size_t)ev.x << 6) + f]);
    }
    if (OUT_BF16) ((ushort*)out_v)[((size_t)node << 6) + f] = f2bf(acc);
    else          ((float*)out_v)[((size_t)node << 6) + f]  = acc;
}

extern "C" void kernel_launch(void* const* d_in, const int* in_sizes, int n_in,
                              void* d_out, int out_size, void* d_ws, size_t ws_size,
                              hipStream_t stream) {
    const float* x   = (const float*)d_in[0];
    const float* ew  = (const float*)d_in[1];
    const int*   src = (const int*)d_in[2];
    const int*   dst = (const int*)d_in[3];
    float* out = (float*)d_out;

    const int n_nodes = in_sizes[0] / D_FEAT;   // 100000
    const int n_edges = in_sizes[1];            // 3200000
    const int nbuck   = (n_nodes + BSIZE - 1) >> BSHIFT;   // 196
    const int n_feat_total = n_nodes * D_FEAT;

    const size_t ed_bytes = (size_t)n_edges * 8;           // 25.6 MB
    const size_t bf_bytes = (size_t)n_feat_total * 2;      // 12.8 MB

    // workspace layout: [region0: inter(25.6MB) -> later x_bf(12.8)+buf1(12.8)]
    //                   [edges 25.6MB][row_ptr][bcount][bbase][bcursor]
    char* ws = (char*)d_ws;
    int2*   inter  = (int2*)ws;
    ushort* x_bf   = (ushort*)ws;
    ushort* buf1   = (ushort*)(ws + bf_bytes);
    ws += (ed_bytes > 2 * bf_bytes ? ed_bytes : 2 * bf_bytes);
    int2* edges    = (int2*)ws;                 ws += ed_bytes;
    int*  row_ptr  = (int*)ws;                  ws += (size_t)(n_nodes + 1) * 4;
    int*  bcount   = (int*)ws;                  ws += 256 * 4;
    int*  bbase    = (int*)ws;                  ws += 256 * 4;
    int*  bcursor  = (int*)ws;

    // --- build dst-sorted CSR (bucketed counting sort); uses inter ---
    hipMemsetAsync(bcount, 0, 256 * 4, stream);
    bucket_hist<<<512, 256, 0, stream>>>(dst, bcount, n_edges);
    bucket_scan<<<1, 256, 0, stream>>>(bcount, bbase, bcursor);
    partition_kernel<<<(n_edges + CHUNK - 1) / CHUNK, 256, 0, stream>>>(
        src, dst, ew, bcursor, inter, n_edges);
    finalize_kernel<<<nbuck, BSIZE, 0, stream>>>(
        inter, bbase, bcount, edges, row_ptr, n_nodes, n_edges);

    // --- convert x to bf16 (inter region now free) ---
    cvt_bf16<<<1024, 256, 0, stream>>>(x, x_bf, n_feat_total);

    // --- 3 gather hops: x_bf -> buf1 -> x_bf -> out(f32) ---
    const int grd = (n_nodes + 3) / 4;
    gather_hop<true ><<<grd, 256, 0, stream>>>(x_bf, edges, row_ptr, buf1, n_nodes);
    gather_hop<true ><<<grd, 256, 0, stream>>>(buf1, edges, row_ptr, x_bf, n_nodes);
    gather_hop<false><<<grd, 256, 0, stream>>>(x_bf, edges, row_ptr, out,  n_nodes);
}